// Round 1
// baseline (727.553 us; speedup 1.0000x reference)
//
#include <hip/hip_runtime.h>

#define N_NODES 100000
#define N_EDGES 1600000

// Workspace layout (floats):
//   [0, 10240)                    : Mcat (160 x 64)  = [W2a ; W1a@W2b ; W1b@W2b]
//   [10240, 10304)                : vb (64)          = b1 @ W2b
//   [16384, 16384+N*64)           : Sx  (N x 64)  segment-sum of x[row]
//   [.. +N*32)                    : Sea (N x 32)  segment-sum of edge_attr
//   [.. +N)                       : deg (N)       in-degree (float)

__global__ void precompute_kernel(const float* __restrict__ W1,
                                  const float* __restrict__ b1,
                                  const float* __restrict__ W2,
                                  float* __restrict__ Mcat,
                                  float* __restrict__ vb) {
    int idx = blockIdx.x * blockDim.x + threadIdx.x;
    if (idx < 160 * 64) {
        int r = idx >> 6, j = idx & 63;
        float acc;
        if (r < 64) {
            acc = W2[r * 64 + j];                       // W2a row
        } else if (r < 128) {
            int i = r - 64;                             // M_x = W1a @ W2b
            acc = 0.f;
            for (int h = 0; h < 128; ++h)
                acc = fmaf(W1[i * 128 + h], W2[(64 + h) * 64 + j], acc);
        } else {
            int i = r - 128;                            // M_ea = W1b @ W2b
            acc = 0.f;
            for (int h = 0; h < 128; ++h)
                acc = fmaf(W1[(64 + i) * 128 + h], W2[(64 + h) * 64 + j], acc);
        }
        Mcat[idx] = acc;
    } else if (idx < 160 * 64 + 64) {
        int j = idx - 160 * 64;                         // vb = b1 @ W2b
        float acc = 0.f;
        for (int h = 0; h < 128; ++h)
            acc = fmaf(b1[h], W2[(64 + h) * 64 + j], acc);
        vb[j] = acc;
    }
}

// 32 lanes per edge: lane j adds x feats j and j+32, ea feat j.
__global__ void scatter_kernel(const float* __restrict__ x,
                               const int* __restrict__ ei,
                               const float* __restrict__ ea,
                               float* __restrict__ Sx,
                               float* __restrict__ Sea,
                               float* __restrict__ deg) {
    int lane = threadIdx.x & 31;
    int egrp = (blockIdx.x * blockDim.x + threadIdx.x) >> 5;
    int stride = (gridDim.x * blockDim.x) >> 5;
    for (int e = egrp; e < N_EDGES; e += stride) {
        int src = ei[e];
        int dst = ei[N_EDGES + e];
        float x0 = x[src * 64 + lane];
        float x1 = x[src * 64 + 32 + lane];
        float a0 = ea[e * 32 + lane];
        atomicAdd(&Sx[dst * 64 + lane], x0);
        atomicAdd(&Sx[dst * 64 + 32 + lane], x1);
        atomicAdd(&Sea[dst * 32 + lane], a0);
        if (lane == 0) atomicAdd(&deg[dst], 1.0f);
    }
}

// out[n][j] = b2[j] + deg[n]*vb[j] + sum_k v[n][k] * Mcat[k][j],
// v[n] = [x[n] (64) ; Sx[n] (64) ; Sea[n] (32)]
__global__ void node_kernel(const float* __restrict__ x,
                            const float* __restrict__ b2,
                            const float* __restrict__ Mcat,
                            const float* __restrict__ vb,
                            const float* __restrict__ Sx,
                            const float* __restrict__ Sea,
                            const float* __restrict__ deg,
                            float* __restrict__ out) {
    __shared__ float m_lds[160 * 64];
    __shared__ float vb_lds[64];
    __shared__ float v_lds[4][160];

    for (int i = threadIdx.x; i < 160 * 64; i += blockDim.x)
        m_lds[i] = Mcat[i];
    if (threadIdx.x < 64) vb_lds[threadIdx.x] = vb[threadIdx.x];

    int sub = threadIdx.x >> 6;   // node within group of 4
    int j = threadIdx.x & 63;     // output feature
    int ngroups = (N_NODES + 3) >> 2;
    for (int g = blockIdx.x; g < ngroups; g += gridDim.x) {
        int nbase = g * 4;
        __syncthreads();
        for (int i = threadIdx.x; i < 4 * 160; i += blockDim.x) {
            int nn = i / 160, k = i - nn * 160;
            int n = nbase + nn;
            float val = 0.f;
            if (n < N_NODES) {
                if (k < 64)       val = x[(size_t)n * 64 + k];
                else if (k < 128) val = Sx[(size_t)n * 64 + (k - 64)];
                else              val = Sea[(size_t)n * 32 + (k - 128)];
            }
            v_lds[nn][k] = val;
        }
        __syncthreads();
        int n = nbase + sub;
        if (n < N_NODES) {
            float acc = b2[j] + deg[n] * vb_lds[j];
            #pragma unroll 8
            for (int k = 0; k < 160; ++k)
                acc = fmaf(v_lds[sub][k], m_lds[k * 64 + j], acc);
            out[(size_t)n * 64 + j] = acc;
        }
    }
}

extern "C" void kernel_launch(void* const* d_in, const int* in_sizes, int n_in,
                              void* d_out, int out_size, void* d_ws, size_t ws_size,
                              hipStream_t stream) {
    const float* x  = (const float*)d_in[0];
    const int*   ei = (const int*)d_in[1];
    const float* ea = (const float*)d_in[2];
    // d_in[3] = u (unused), d_in[4] = batch (unused)
    const float* W1 = (const float*)d_in[5];
    const float* b1 = (const float*)d_in[6];
    const float* W2 = (const float*)d_in[7];
    const float* b2 = (const float*)d_in[8];

    float* ws   = (float*)d_ws;
    float* Mcat = ws;
    float* vb   = ws + 10240;
    float* Sx   = ws + 16384;
    float* Sea  = Sx + (size_t)N_NODES * 64;
    float* deg  = Sea + (size_t)N_NODES * 32;

    // Zero the accumulators every call (ws is poisoned once, never restored).
    hipMemsetAsync(Sx, 0, (size_t)N_NODES * 97 * sizeof(float), stream);

    precompute_kernel<<<41, 256, 0, stream>>>(W1, b1, W2, Mcat, vb);
    scatter_kernel<<<2048, 256, 0, stream>>>(x, ei, ea, Sx, Sea, deg);
    node_kernel<<<2048, 256, 0, stream>>>(x, b2, Mcat, vb, Sx, Sea, deg, (float*)d_out);
}

// Round 2
// 369.211 us; speedup vs baseline: 1.9706x; 1.9706x over previous
//
#include <hip/hip_runtime.h>

#define NN 100000
#define NE 1600000
#define NB ((NN + 1023) / 1024)   // 98 scan blocks

// Workspace layout (4-byte words):
//   [0, 10240)            Mcat (160 x 64 f32) = [W2a ; W1a@W2b ; W1b@W2b]
//   [10240, 10304)        vb (64 f32) = b1 @ W2b
//   [16384, +NN)          counts (int)    -- in-degree, also used by gather
//   [16384+NN, +NN)       row_start (int)
//   [16384+2NN, +NN)      cursor (int)
//   [16384+3NN, +1024)    block_sums (int)
//   [16384+3NN+1024, ...) pairs (int2 per edge: src, edge_id), 2*NE words

__global__ void precompute_kernel(const float* __restrict__ W1,
                                  const float* __restrict__ b1,
                                  const float* __restrict__ W2,
                                  float* __restrict__ Mcat,
                                  float* __restrict__ vb) {
    int idx = blockIdx.x * blockDim.x + threadIdx.x;
    if (idx < 160 * 64) {
        int r = idx >> 6, j = idx & 63;
        float acc;
        if (r < 64) {
            acc = W2[r * 64 + j];                       // W2a row
        } else if (r < 128) {
            int i = r - 64;                             // W1a @ W2b
            acc = 0.f;
            for (int h = 0; h < 128; ++h)
                acc = fmaf(W1[i * 128 + h], W2[(64 + h) * 64 + j], acc);
        } else {
            int i = r - 128;                            // W1b @ W2b
            acc = 0.f;
            for (int h = 0; h < 128; ++h)
                acc = fmaf(W1[(64 + i) * 128 + h], W2[(64 + h) * 64 + j], acc);
        }
        Mcat[idx] = acc;
    } else if (idx < 160 * 64 + 64) {
        int j = idx - 160 * 64;                         // vb = b1 @ W2b
        float acc = 0.f;
        for (int h = 0; h < 128; ++h)
            acc = fmaf(b1[h], W2[(64 + h) * 64 + j], acc);
        vb[j] = acc;
    }
}

__global__ void hist_kernel(const int* __restrict__ ei, int* __restrict__ counts) {
    int i = blockIdx.x * blockDim.x + threadIdx.x;
    int stride = gridDim.x * blockDim.x;
    for (int e = i; e < NE; e += stride)
        atomicAdd(&counts[ei[NE + e]], 1);
}

__global__ void scan1_kernel(const int* __restrict__ counts,
                             int* __restrict__ row_start,
                             int* __restrict__ block_sums) {
    __shared__ int s[1024];
    int tid = threadIdx.x;
    int i = blockIdx.x * 1024 + tid;
    int v = (i < NN) ? counts[i] : 0;
    s[tid] = v;
    __syncthreads();
    for (int off = 1; off < 1024; off <<= 1) {
        int t = (tid >= off) ? s[tid - off] : 0;
        __syncthreads();
        s[tid] += t;
        __syncthreads();
    }
    if (i < NN) row_start[i] = s[tid] - v;              // exclusive within block
    if (tid == 1023) block_sums[blockIdx.x] = s[1023];
}

__global__ void scan2_kernel(int* __restrict__ block_sums) {
    __shared__ int s[128];
    int tid = threadIdx.x;
    int v = (tid < NB) ? block_sums[tid] : 0;
    s[tid] = v;
    __syncthreads();
    for (int off = 1; off < 128; off <<= 1) {
        int t = (tid >= off) ? s[tid - off] : 0;
        __syncthreads();
        s[tid] += t;
        __syncthreads();
    }
    if (tid < NB) block_sums[tid] = s[tid] - v;         // exclusive block offsets
}

__global__ void scan3_kernel(int* __restrict__ row_start,
                             int* __restrict__ cursor,
                             const int* __restrict__ block_sums) {
    int i = blockIdx.x * 1024 + threadIdx.x;
    if (i < NN) {
        int r = row_start[i] + block_sums[blockIdx.x];
        row_start[i] = r;
        cursor[i] = r;
    }
}

__global__ void fill_kernel(const int* __restrict__ ei,
                            int* __restrict__ cursor,
                            int2* __restrict__ pairs) {
    int i = blockIdx.x * blockDim.x + threadIdx.x;
    int stride = gridDim.x * blockDim.x;
    for (int e = i; e < NE; e += stride) {
        int src = ei[e];
        int dst = ei[NE + e];
        int pos = atomicAdd(&cursor[dst], 1);
        pairs[pos] = make_int2(src, e);
    }
}

// One wave (64 lanes) per node: gather + accumulate in registers, then GEMV
// against LDS-cached Mcat. No inter-wave sync in the node loop.
__global__ __launch_bounds__(1024, 2)
void gather_kernel(const float* __restrict__ x,
                   const float* __restrict__ ea,
                   const float* __restrict__ b2,
                   const float* __restrict__ Mcat,
                   const float* __restrict__ vb,
                   const int* __restrict__ row_start,
                   const int* __restrict__ counts,
                   const int2* __restrict__ pairs,
                   float* __restrict__ out) {
    __shared__ float m_lds[160 * 64];                   // 40 KB
    __shared__ float vb_lds[64];
    __shared__ float b2_lds[64];
    __shared__ float v_lds[16][160];                    // per-wave scratch

    for (int i = threadIdx.x; i < 160 * 64; i += blockDim.x)
        m_lds[i] = Mcat[i];
    if (threadIdx.x < 64) {
        vb_lds[threadIdx.x] = vb[threadIdx.x];
        b2_lds[threadIdx.x] = b2[threadIdx.x];
    }
    __syncthreads();

    int wave = threadIdx.x >> 6;
    int lane = threadIdx.x & 63;
    int elane = lane & 31;
    int nwaves_total = gridDim.x * 16;

    for (int n = blockIdx.x * 16 + wave; n < NN; n += nwaves_total) {
        int start = row_start[n];
        int dcnt = counts[n];
        float xacc = 0.f, eacc = 0.f;
        int i = 0;
        for (; i + 1 < dcnt; i += 2) {                  // 2 edges per iter
            int2 p0 = pairs[start + i];
            int2 p1 = pairs[start + i + 1];
            xacc += x[(size_t)p0.x * 64 + lane];
            xacc += x[(size_t)p1.x * 64 + lane];
            int esel = (lane < 32) ? p0.y : p1.y;       // half-wave per edge
            eacc += ea[(size_t)esel * 32 + elane];
        }
        if (i < dcnt) {
            int2 p0 = pairs[start + i];
            xacc += x[(size_t)p0.x * 64 + lane];
            if (lane < 32) eacc += ea[(size_t)p0.y * 32 + elane];
        }
        float eo = __shfl_xor(eacc, 32);                // combine half-waves

        v_lds[wave][lane] = x[(size_t)n * 64 + lane];   // self features
        v_lds[wave][64 + lane] = xacc;                  // Sx
        if (lane < 32) v_lds[wave][128 + lane] = eacc + eo;  // Sea
        __threadfence_block();                          // within-wave LDS RAW

        float acc = b2_lds[lane] + (float)dcnt * vb_lds[lane];
        #pragma unroll 8
        for (int k = 0; k < 160; ++k)
            acc = fmaf(v_lds[wave][k], m_lds[k * 64 + lane], acc);
        out[(size_t)n * 64 + lane] = acc;
    }
}

extern "C" void kernel_launch(void* const* d_in, const int* in_sizes, int n_in,
                              void* d_out, int out_size, void* d_ws, size_t ws_size,
                              hipStream_t stream) {
    const float* x  = (const float*)d_in[0];
    const int*   ei = (const int*)d_in[1];
    const float* ea = (const float*)d_in[2];
    const float* W1 = (const float*)d_in[5];
    const float* b1 = (const float*)d_in[6];
    const float* W2 = (const float*)d_in[7];
    const float* b2 = (const float*)d_in[8];

    float* ws        = (float*)d_ws;
    float* Mcat      = ws;
    float* vb        = ws + 10240;
    int*   counts    = (int*)(ws + 16384);
    int*   row_start = counts + NN;
    int*   cursor    = row_start + NN;
    int*   block_sums= cursor + NN;
    int2*  pairs     = (int2*)(block_sums + 1024);

    hipMemsetAsync(counts, 0, NN * sizeof(int), stream);

    precompute_kernel<<<41, 256, 0, stream>>>(W1, b1, W2, Mcat, vb);
    hist_kernel<<<2048, 256, 0, stream>>>(ei, counts);
    scan1_kernel<<<NB, 1024, 0, stream>>>(counts, row_start, block_sums);
    scan2_kernel<<<1, 128, 0, stream>>>(block_sums);
    scan3_kernel<<<NB, 1024, 0, stream>>>(row_start, cursor, block_sums);
    fill_kernel<<<2048, 256, 0, stream>>>(ei, cursor, pairs);
    gather_kernel<<<512, 1024, 0, stream>>>(x, ea, b2, Mcat, vb,
                                            row_start, counts, pairs,
                                            (float*)d_out);
}